// Round 2
// baseline (668.728 us; speedup 1.0000x reference)
//
#include <hip/hip_runtime.h>

// Problem constants (E,B,C,H,W) = (3,8,10,512,512), HIDDEN=256
#define HWQ   262144      // H*W
#define CHW   2621440     // C*H*W
#define BCHW  20971520    // B*C*H*W
#define NTOT  2097152     // B*H*W
#define NPT   4           // elements per thread
#define NTHREAD (NTOT / NPT)   // 524288 threads total

typedef float v2f __attribute__((ext_vector_type(2)));

// Single fused kernel. No d_ws usage at all (round-1 failure mode: writes to
// d_ws corrupted persistent harness state after call 1 — call 1 was exact,
// all later calls consistently wrong). Weights are staged per-block into LDS:
// row j holds 18 v2f = {(w1[0,j],w1[1,j]) .. (w1[28,j],w1[29,j]),
//                       (b1[j], w2[j][0]), (w2[j][1], w2[j][2]), (0,0)}
// Row stride 144 B (16B-aligned for every j). Inner-loop reads are
// wave-uniform -> LDS broadcast, conflict-free.
__global__ __launch_bounds__(256)
void mlp_select_fused(const float* __restrict__ inputs,
                      const float* __restrict__ w1,
                      const float* __restrict__ b1,
                      const float* __restrict__ w2,
                      const float* __restrict__ b2,
                      float* __restrict__ out0,
                      float* __restrict__ out1) {
    __shared__ v2f smem[256 * 18];          // 36,864 B LDS

    // ---- one-time weight staging (coalesced in j across lanes) ----
    {
        const int j = threadIdx.x;          // 0..255 hidden unit
        v2f* row = &smem[j * 18];
        #pragma unroll
        for (int kk = 0; kk < 15; ++kk) {
            v2f t;
            t.x = w1[(2 * kk    ) * 256 + j];
            t.y = w1[(2 * kk + 1) * 256 + j];
            row[kk] = t;
        }
        v2f t15; t15.x = b1[j];        t15.y = w2[j * 3 + 0]; row[15] = t15;
        v2f t16; t16.x = w2[j * 3 + 1]; t16.y = w2[j * 3 + 2]; row[16] = t16;
        v2f t17; t17.x = 0.f;           t17.y = 0.f;           row[17] = t17;
    }
    __syncthreads();

    const int tid = blockIdx.x * 256 + threadIdx.x;

    // ---- gather x: 30 lane-coalesced strided planes per element ----
    v2f x2[NPT][15];
    int q[NPT], r[NPT];
    #pragma unroll
    for (int m = 0; m < NPT; ++m) {
        int n = tid + m * NTHREAD;
        q[m] = n >> 18;            // b index (n / HW)
        r[m] = n & (HWQ - 1);      // hw index
        const float* __restrict__ p = inputs + (long)q[m] * CHW + r[m];
        #pragma unroll
        for (int k = 0; k < 30; ++k) {
            const int e = k / 10, c = k % 10;   // compile-time after unroll
            float v = p[(long)e * BCHW + (long)c * HWQ];
            if (k & 1) x2[m][k / 2].y = v; else x2[m][k / 2].x = v;
        }
    }

    const float b20 = b2[0], b21 = b2[1], b22 = b2[2];
    float l[NPT][3];
    #pragma unroll
    for (int m = 0; m < NPT; ++m) { l[m][0] = b20; l[m][1] = b21; l[m][2] = b22; }

    // ---- fused MLP: h=relu(x@w1+b1); logits=h@w2+b2, one hidden unit j at a
    // time. Inner product paired over k -> v_pk_fma_f32 (2x fp32 rate). ----
    #pragma unroll 2
    for (int j = 0; j < 256; ++j) {
        const v2f* __restrict__ wrow = &smem[j * 18];   // uniform -> broadcast
        const v2f bw  = wrow[15];   // {b1[j], w2[j][0]}
        const v2f w12 = wrow[16];   // {w2[j][1], w2[j][2]}

        v2f h2[NPT];
        #pragma unroll
        for (int m = 0; m < NPT; ++m) { v2f t; t.x = bw.x; t.y = 0.f; h2[m] = t; }

        #pragma unroll
        for (int kk = 0; kk < 15; ++kk) {
            const v2f wk = wrow[kk];
            #pragma unroll
            for (int m = 0; m < NPT; ++m)
                h2[m] = __builtin_elementwise_fma(x2[m][kk], wk, h2[m]);
        }

        #pragma unroll
        for (int m = 0; m < NPT; ++m) {
            const float hm = fmaxf(h2[m].x + h2[m].y, 0.f);
            l[m][0] = fmaf(hm, bw.y,  l[m][0]);
            l[m][1] = fmaf(hm, w12.x, l[m][1]);
            l[m][2] = fmaf(hm, w12.y, l[m][2]);
        }
    }

    // ---- argmax (numpy first-max semantics) + scatter winning expert ----
    #pragma unroll
    for (int m = 0; m < NPT; ++m) {
        int sel = 0;
        float best = l[m][0];
        if (l[m][1] > best) { best = l[m][1]; sel = 1; }
        if (l[m][2] > best) { sel = 2; }
        const bool s1 = (sel == 1);
        const bool s2 = (sel == 2);
        float* __restrict__ o = out0 + (long)q[m] * CHW + r[m];
        #pragma unroll
        for (int c = 0; c < 10; ++c) {
            // constant component indexing after unroll -> v_cndmask chains
            const int k0 = c, k1 = 10 + c, k2 = 20 + c;
            const float v0 = (k0 & 1) ? x2[m][k0 / 2].y : x2[m][k0 / 2].x;
            const float v1 = (k1 & 1) ? x2[m][k1 / 2].y : x2[m][k1 / 2].x;
            const float v2 = (k2 & 1) ? x2[m][k2 / 2].y : x2[m][k2 / 2].x;
            float v = s2 ? v2 : (s1 ? v1 : v0);
            o[(long)c * HWQ] = v;
        }
        out1[tid + m * NTHREAD] = (float)sel;
    }
}

extern "C" void kernel_launch(void* const* d_in, const int* in_sizes, int n_in,
                              void* d_out, int out_size, void* d_ws, size_t ws_size,
                              hipStream_t stream) {
    const float* inputs = (const float*)d_in[0];   // (3,8,10,512,512)
    const float* w1     = (const float*)d_in[1];   // (30,256)
    const float* b1     = (const float*)d_in[2];   // (256,)
    const float* w2     = (const float*)d_in[3];   // (256,3)
    const float* b2     = (const float*)d_in[4];   // (3,)

    float* out0 = (float*)d_out;           // (8,10,512,512)
    float* out1 = out0 + BCHW;             // (8,512,512) selections as float

    mlp_select_fused<<<NTOT / (256 * NPT), 256, 0, stream>>>(
        inputs, w1, b1, w2, b2, out0, out1);
}